// Round 12
// baseline (220.107 us; speedup 1.0000x reference)
//
#include <hip/hip_runtime.h>

// Problem: B=4, S=2048, D_IN=1024, D_OUT=1024, H=16, DH=64
#define NB 4
#define NS 2048
#define NH 16
#define NDH 64

typedef short bf16x8 __attribute__((ext_vector_type(8)));
typedef short bf16x4 __attribute__((ext_vector_type(4)));
typedef float f32x4 __attribute__((ext_vector_type(4)));
typedef unsigned short u16;
typedef unsigned int u32;

static __device__ __forceinline__ u16 f2bf(float f) {
  unsigned u = __float_as_uint(f);
  u += 0x7fffu + ((u >> 16) & 1u);  // round-to-nearest-even
  return (u16)(u >> 16);
}

#define GLDS(gp, lp) __builtin_amdgcn_global_load_lds( \
    (const __attribute__((address_space(1))) void*)(gp), \
    (__attribute__((address_space(3))) void*)(lp), 16, 0, 0)

// ---------------- fp32 -> bf16 elementwise convert ----------------
__global__ void cvt_k(const float* __restrict__ in, u16* __restrict__ out, int n) {
  int i = (blockIdx.x * 256 + threadIdx.x) * 8;
  if (i >= n) return;
  float4 a = *(const float4*)&in[i];
  float4 b = *(const float4*)&in[i + 4];
  bf16x8 u;
  u[0] = (short)f2bf(a.x); u[1] = (short)f2bf(a.y);
  u[2] = (short)f2bf(a.z); u[3] = (short)f2bf(a.w);
  u[4] = (short)f2bf(b.x); u[5] = (short)f2bf(b.y);
  u[6] = (short)f2bf(b.z); u[7] = (short)f2bf(b.w);
  *(bf16x8*)&out[i] = u;
}

// ---------------- fp32 [R][C] -> bf16 [C][R] transpose-convert ----------------
__global__ void trcvt_k(const float* __restrict__ in, u16* __restrict__ out, int R, int C) {
  __shared__ float t[32][33];
  int c0 = blockIdx.x * 32, r0 = blockIdx.y * 32;
  int tx = threadIdx.x & 7, ty = threadIdx.x >> 3;
  float4 v = *(const float4*)&in[(size_t)(r0 + ty) * C + c0 + tx * 4];
  t[ty][tx * 4 + 0] = v.x; t[ty][tx * 4 + 1] = v.y;
  t[ty][tx * 4 + 2] = v.z; t[ty][tx * 4 + 3] = v.w;
  __syncthreads();
  ushort4 o;
  o.x = f2bf(t[tx * 4 + 0][ty]); o.y = f2bf(t[tx * 4 + 1][ty]);
  o.z = f2bf(t[tx * 4 + 2][ty]); o.w = f2bf(t[tx * 4 + 3][ty]);
  *(ushort4*)&out[(size_t)(c0 + ty) * R + r0 + tx * 4] = o;
}

#define BAR   do { __builtin_amdgcn_s_barrier(); __builtin_amdgcn_sched_barrier(0); } while (0)
#define VMC(n) do { asm volatile("s_waitcnt vmcnt(" #n ")" ::: "memory"); \
                    __builtin_amdgcn_sched_barrier(0); } while (0)

// ---------------- QKV GEMM: 256x128 tile, BK=64, 8-phase counted-vmcnt ----------------
// A [8192][1024], Bt [3072][1024] row-major. 8 waves; wave (wr,wc) owns 64x64.
// 3 LDS buffers (144KB), prefetch depth 2; per K-tile 4 phases of
// {ds_read subtile | issue GLDS(t+2) -> s_barrier -> setprio MFMA -> s_barrier},
// one vmcnt(6) per tile (T3+T4). LDS content XOR-swizzled (byte ^= (row&7)<<4),
// staged via pre-swizzled GLDS source (rule #21; 0 bank conflicts measured R11).
// Epilogue: scatter Q (pre-scaled 0.125*log2e), K, VT.
__global__ __launch_bounds__(512)
void gemm8_k(const u16* __restrict__ A, const u16* __restrict__ Bt,
             u16* __restrict__ Qo, u16* __restrict__ Ko, u16* __restrict__ VTo) {
  constexpr int Kd = 1024, NK = 16;
  __shared__ __align__(16) u16 As[3][256 * 64];   // 96 KB
  __shared__ __align__(16) u16 Bs[3][128 * 64];   // 48 KB
  const int tid = threadIdx.x, w = tid >> 6, l = tid & 63;
  const int lr = l & 15, lg = l >> 4;
  const int wr = w >> 1, wc = w & 1;
  const int m0 = blockIdx.y * 256, n0 = blockIdx.x * 128;
  const int swz = (lr & 7) << 4;

  // staging maps: round r2 covers rows [r2*64, r2*64+64); source pre-swizzled
  int aSrc[4], bSrc[2], dOff[4];
#pragma unroll
  for (int r2 = 0; r2 < 4; ++r2) {
    int c = r2 * 512 + tid;
    int row = c >> 3;
    int sb = ((c & 7) * 16) ^ ((row & 7) << 4);
    aSrc[r2] = row * Kd + (sb >> 1);
    if (r2 < 2) bSrc[r2] = row * Kd + (sb >> 1);
    dOff[r2] = r2 * 8192 + w * 1024;     // wave-uniform byte base
  }

#define STG_A(t, r2) GLDS(A  + (size_t)m0 * Kd + (t) * 64 + aSrc[r2], (char*)As[(t) % 3] + dOff[r2])
#define STG_B(t, r2) GLDS(Bt + (size_t)n0 * Kd + (t) * 64 + bSrc[r2], (char*)Bs[(t) % 3] + dOff[r2])
#define RD_A(mi, kk) (*(const bf16x8*)((const char*)As[cur] + \
    ((wr * 64 + (mi) * 16 + lr) * 128 + (((kk) * 64 + lg * 16) ^ swz))))
#define RD_B(ni, kk) (*(const bf16x8*)((const char*)Bs[cur] + \
    ((wc * 64 + (ni) * 16 + lr) * 128 + (((kk) * 64 + lg * 16) ^ swz))))

  f32x4 acc[4][4] = {};

  // prologue: stage tiles 0 and 1 (6 loads each)
  STG_A(0, 0); STG_A(0, 1); STG_A(0, 2); STG_A(0, 3); STG_B(0, 0); STG_B(0, 1);
  STG_A(1, 0); STG_A(1, 1); STG_A(1, 2); STG_A(1, 3); STG_B(1, 0); STG_B(1, 1);
  VMC(6);   // tile 0 landed (tile 1's 6 in flight)
  BAR;

  for (int t = 0; t < NK; ++t) {
    const int cur = t % 3;
    const bool pf = (t + 2 < NK);
    bf16x8 af0, af1, af2, af3, b0, b1, b2, b3;

    // ---- ph0: kk=0, ni in {0,1} ----
    af0 = RD_A(0, 0); af1 = RD_A(1, 0); af2 = RD_A(2, 0); af3 = RD_A(3, 0);
    b0 = RD_B(0, 0); b1 = RD_B(1, 0);
    if (pf) { STG_A(t + 2, 0); STG_A(t + 2, 1); }
    BAR;
    __builtin_amdgcn_s_setprio(1);
    acc[0][0] = __builtin_amdgcn_mfma_f32_16x16x32_bf16(af0, b0, acc[0][0], 0, 0, 0);
    acc[1][0] = __builtin_amdgcn_mfma_f32_16x16x32_bf16(af1, b0, acc[1][0], 0, 0, 0);
    acc[2][0] = __builtin_amdgcn_mfma_f32_16x16x32_bf16(af2, b0, acc[2][0], 0, 0, 0);
    acc[3][0] = __builtin_amdgcn_mfma_f32_16x16x32_bf16(af3, b0, acc[3][0], 0, 0, 0);
    acc[0][1] = __builtin_amdgcn_mfma_f32_16x16x32_bf16(af0, b1, acc[0][1], 0, 0, 0);
    acc[1][1] = __builtin_amdgcn_mfma_f32_16x16x32_bf16(af1, b1, acc[1][1], 0, 0, 0);
    acc[2][1] = __builtin_amdgcn_mfma_f32_16x16x32_bf16(af2, b1, acc[2][1], 0, 0, 0);
    acc[3][1] = __builtin_amdgcn_mfma_f32_16x16x32_bf16(af3, b1, acc[3][1], 0, 0, 0);
    __builtin_amdgcn_s_setprio(0);
    BAR;

    // ---- ph1: kk=0, ni in {2,3} ----
    b2 = RD_B(2, 0); b3 = RD_B(3, 0);
    if (pf) { STG_A(t + 2, 2); STG_A(t + 2, 3); }
    BAR;
    __builtin_amdgcn_s_setprio(1);
    acc[0][2] = __builtin_amdgcn_mfma_f32_16x16x32_bf16(af0, b2, acc[0][2], 0, 0, 0);
    acc[1][2] = __builtin_amdgcn_mfma_f32_16x16x32_bf16(af1, b2, acc[1][2], 0, 0, 0);
    acc[2][2] = __builtin_amdgcn_mfma_f32_16x16x32_bf16(af2, b2, acc[2][2], 0, 0, 0);
    acc[3][2] = __builtin_amdgcn_mfma_f32_16x16x32_bf16(af3, b2, acc[3][2], 0, 0, 0);
    acc[0][3] = __builtin_amdgcn_mfma_f32_16x16x32_bf16(af0, b3, acc[0][3], 0, 0, 0);
    acc[1][3] = __builtin_amdgcn_mfma_f32_16x16x32_bf16(af1, b3, acc[1][3], 0, 0, 0);
    acc[2][3] = __builtin_amdgcn_mfma_f32_16x16x32_bf16(af2, b3, acc[2][3], 0, 0, 0);
    acc[3][3] = __builtin_amdgcn_mfma_f32_16x16x32_bf16(af3, b3, acc[3][3], 0, 0, 0);
    __builtin_amdgcn_s_setprio(0);
    BAR;

    // ---- ph2: kk=1, ni in {0,1} ----
    af0 = RD_A(0, 1); af1 = RD_A(1, 1); af2 = RD_A(2, 1); af3 = RD_A(3, 1);
    b0 = RD_B(0, 1); b1 = RD_B(1, 1);
    if (pf) STG_B(t + 2, 0);
    BAR;
    __builtin_amdgcn_s_setprio(1);
    acc[0][0] = __builtin_amdgcn_mfma_f32_16x16x32_bf16(af0, b0, acc[0][0], 0, 0, 0);
    acc[1][0] = __builtin_amdgcn_mfma_f32_16x16x32_bf16(af1, b0, acc[1][0], 0, 0, 0);
    acc[2][0] = __builtin_amdgcn_mfma_f32_16x16x32_bf16(af2, b0, acc[2][0], 0, 0, 0);
    acc[3][0] = __builtin_amdgcn_mfma_f32_16x16x32_bf16(af3, b0, acc[3][0], 0, 0, 0);
    acc[0][1] = __builtin_amdgcn_mfma_f32_16x16x32_bf16(af0, b1, acc[0][1], 0, 0, 0);
    acc[1][1] = __builtin_amdgcn_mfma_f32_16x16x32_bf16(af1, b1, acc[1][1], 0, 0, 0);
    acc[2][1] = __builtin_amdgcn_mfma_f32_16x16x32_bf16(af2, b1, acc[2][1], 0, 0, 0);
    acc[3][1] = __builtin_amdgcn_mfma_f32_16x16x32_bf16(af3, b1, acc[3][1], 0, 0, 0);
    __builtin_amdgcn_s_setprio(0);
    BAR;

    // ---- ph3: kk=1, ni in {2,3}; per-tile counted vmcnt ----
    b2 = RD_B(2, 1); b3 = RD_B(3, 1);
    if (pf) STG_B(t + 2, 1);
    BAR;
    __builtin_amdgcn_s_setprio(1);
    acc[0][2] = __builtin_amdgcn_mfma_f32_16x16x32_bf16(af0, b2, acc[0][2], 0, 0, 0);
    acc[1][2] = __builtin_amdgcn_mfma_f32_16x16x32_bf16(af1, b2, acc[1][2], 0, 0, 0);
    acc[2][2] = __builtin_amdgcn_mfma_f32_16x16x32_bf16(af2, b2, acc[2][2], 0, 0, 0);
    acc[3][2] = __builtin_amdgcn_mfma_f32_16x16x32_bf16(af3, b2, acc[3][2], 0, 0, 0);
    acc[0][3] = __builtin_amdgcn_mfma_f32_16x16x32_bf16(af0, b3, acc[0][3], 0, 0, 0);
    acc[1][3] = __builtin_amdgcn_mfma_f32_16x16x32_bf16(af1, b3, acc[1][3], 0, 0, 0);
    acc[2][3] = __builtin_amdgcn_mfma_f32_16x16x32_bf16(af2, b3, acc[2][3], 0, 0, 0);
    acc[3][3] = __builtin_amdgcn_mfma_f32_16x16x32_bf16(af3, b3, acc[3][3], 0, 0, 0);
    __builtin_amdgcn_s_setprio(0);
    if (t + 2 < NK) { VMC(6); } else { VMC(0); }   // next tile landed; t+2 in flight
    BAR;
  }

  // ---- epilogue: scatter Q/K/VT (verified maps) ----
#pragma unroll
  for (int mi = 0; mi < 4; ++mi) {
#pragma unroll
    for (int ni = 0; ni < 4; ++ni) {
#pragma unroll
      for (int r = 0; r < 4; ++r) {
        int gm = m0 + wr * 64 + mi * 16 + lg * 4 + r;
        int gn = n0 + wc * 64 + ni * 16 + lr;
        float v = acc[mi][ni][r];
        int which = gn >> 10, hd = gn & 1023;
        int b = gm >> 11, s = gm & 2047;
        int bh = b * NH + (hd >> 6), dh = hd & 63;
        if (which == 0)      Qo[((size_t)bh * NS + s) * NDH + dh] = f2bf(v * 0.1803368801111204f);
        else if (which == 1) Ko[((size_t)bh * NS + s) * NDH + dh] = f2bf(v);
        else                 VTo[((size_t)bh * NDH + dh) * NS + s] = f2bf(v);
      }
    }
  }
#undef STG_A
#undef STG_B
#undef RD_A
#undef RD_B
}

// ---------------- out-proj GEMM (R11 structure, BK=64, swizzled) ----------------
template<int WM>
__global__ __launch_bounds__(WM * 128)
void gemm_k(const u16* __restrict__ A, const u16* __restrict__ Bt,
            int M, int N, int K,
            float* __restrict__ Co, const float* __restrict__ bias) {
  constexpr int T  = WM * 128;
  constexpr int BM = WM * 64;
  constexpr int RA = 4;
  constexpr int RB = 1024 / T;
  __shared__ __align__(16) u16 As[BM * 64];
  __shared__ __align__(16) u16 Bs[128 * 64];
  const int tid = threadIdx.x;
  const int w = tid >> 6, l = tid & 63;
  const int lr = l & 15, lg = l >> 4;
  const int wr = w >> 1, wc = w & 1;
  const int m0 = blockIdx.y * BM, n0 = blockIdx.x * 128;
  const int swz = (lr & 7) << 4;

  f32x4 acc[4][4] = {};

  const int nk = K >> 6;
  for (int kt = 0; kt < nk; ++kt) {
    __syncthreads();
    const int k0 = kt * 64;
#pragma unroll
    for (int r2 = 0; r2 < RA; ++r2) {
      int c = r2 * T + tid;
      int row = c >> 3;
      int scolb = ((c & 7) * 16) ^ ((row & 7) << 4);
      GLDS(A + (size_t)(m0 + row) * K + k0 + (scolb >> 1),
           (char*)As + (size_t)r2 * T * 16 + w * 1024);
    }
#pragma unroll
    for (int r2 = 0; r2 < RB; ++r2) {
      int c = r2 * T + tid;
      int row = c >> 3;
      int scolb = ((c & 7) * 16) ^ ((row & 7) << 4);
      GLDS(Bt + (size_t)(n0 + row) * K + k0 + (scolb >> 1),
           (char*)Bs + (size_t)r2 * T * 16 + w * 1024);
    }
    __syncthreads();

#pragma unroll
    for (int kk = 0; kk < 2; ++kk) {
      bf16x8 af[4];
#pragma unroll
      for (int mi = 0; mi < 4; ++mi)
        af[mi] = *(const bf16x8*)((const char*)As +
                  ((wr * 64 + mi * 16 + lr) * 128 + ((kk * 64 + lg * 16) ^ swz)));
#pragma unroll
      for (int ni = 0; ni < 4; ++ni) {
        bf16x8 bfr = *(const bf16x8*)((const char*)Bs +
                  ((wc * 64 + ni * 16 + lr) * 128 + ((kk * 64 + lg * 16) ^ swz)));
#pragma unroll
        for (int mi = 0; mi < 4; ++mi)
          acc[mi][ni] = __builtin_amdgcn_mfma_f32_16x16x32_bf16(af[mi], bfr, acc[mi][ni], 0, 0, 0);
      }
    }
  }

#pragma unroll
  for (int mi = 0; mi < 4; ++mi)
#pragma unroll
    for (int ni = 0; ni < 4; ++ni)
#pragma unroll
      for (int r = 0; r < 4; ++r) {
        int gm = m0 + wr * 64 + mi * 16 + lg * 4 + r;
        int gn = n0 + wc * 64 + ni * 16 + lr;
        Co[(size_t)gm * N + gn] = acc[mi][ni][r] + bias[gn];
      }
}

// ---------------- causal flash attention (unchanged from R9/R11) ----------------
__global__ __launch_bounds__(512)
void attn_k(const u16* __restrict__ Q, const u16* __restrict__ Kg,
            const u16* __restrict__ VTg, u16* __restrict__ CTX) {
  const int bh = blockIdx.x;
  const int pr = blockIdx.y;
  const int tid = threadIdx.x, w = tid >> 6, l = tid & 63;
  const int lr = l & 15, lg = l >> 4;
  const u16* Qh  = Q   + (size_t)bh * NS * NDH;
  const u16* Kh  = Kg  + (size_t)bh * NS * NDH;
  const u16* Vth = VTg + (size_t)bh * NDH * NS;

  __shared__ __align__(16) u16 Ks[2][64 * 64];
  __shared__ __align__(16) u16 Vs[2][64 * 64];

  const int srow_ = tid >> 3;
  const int colb  = (tid & 7) * 16;
  const int scolb = colb ^ ((srow_ & 7) << 4);
  const int kSrcOff = srow_ * NDH + (scolb >> 1);
  const int vSrcOff = srow_ * NS + (scolb >> 1);
  const int ldsOff  = w * 1024;

#define STAGE(t, buf) do {                                          \
    GLDS(Kh  + (size_t)(t) * 64 * NDH + kSrcOff, (char*)Ks[buf] + ldsOff); \
    GLDS(Vth + (size_t)(t) * 64       + vSrcOff, (char*)Vs[buf] + ldsOff); \
  } while (0)

  const int swz = (lr & 7) << 4;
  const int b = bh >> 4, h = bh & 15;

  for (int pass = 0; pass < 2; ++pass) {
    const int qt = pass == 0 ? pr : 15 - pr;

    const int qrow = qt * 128 + w * 16 + lr;
    bf16x8 qf[2];
    qf[0] = *(const bf16x8*)&Qh[(size_t)qrow * NDH + 0 * 32 + lg * 8];
    qf[1] = *(const bf16x8*)&Qh[(size_t)qrow * NDH + 1 * 32 + lg * 8];

    f32x4 o[4] = {};
    float lrun = 0.f;
    const int qmin = qt * 128 + w * 16;

    __syncthreads();
    STAGE(0, 0);
    __syncthreads();

    const int NT = 2 * qt + 2;
    for (int kt = 0; kt < NT; ++kt) {
      const int cur = kt & 1;
      if (kt + 1 < NT) STAGE(kt + 1, cur ^ 1);

      f32x4 sc[4] = {};
#pragma unroll
      for (int kk = 0; kk < 2; ++kk) {
#pragma unroll
        for (int kg = 0; kg < 4; ++kg) {
          bf16x8 kf = *(const bf16x8*)((const char*)Ks[cur] +
                       ((kg * 16 + lr) * 128 + ((kk * 64 + lg * 16) ^ swz)));
          sc[kg] = __builtin_amdgcn_mfma_f32_16x16x32_bf16(kf, qf[kk], sc[kg], 0, 0, 0);
        }
      }

      float sum = 0.f;
      if (kt * 64 + 63 > qmin) {
#pragma unroll
        for (int kg = 0; kg < 4; ++kg)
#pragma unroll
          for (int r = 0; r < 4; ++r) {
            int kglob = kt * 64 + kg * 16 + lg * 4 + r;
            float e = (kglob > qrow) ? 0.f : exp2f(sc[kg][r]);
            sc[kg][r] = e; sum += e;
          }
      } else {
#pragma unroll
        for (int kg = 0; kg < 4; ++kg)
#pragma unroll
          for (int r = 0; r < 4; ++r) {
            float e = exp2f(sc[kg][r]);
            sc[kg][r] = e; sum += e;
          }
      }
      lrun += sum;

#pragma unroll
      for (int half = 0; half < 2; ++half) {
        union { u32 wd[4]; bf16x8 v; } pk;
#pragma unroll
        for (int w2 = 0; w2 < 4; ++w2) {
          float lo = sc[half * 2 + (w2 >> 1)][2 * (w2 & 1)];
          float hi = sc[half * 2 + (w2 >> 1)][2 * (w2 & 1) + 1];
          asm("v_cvt_pk_bf16_f32 %0, %1, %2" : "=v"(pk.wd[w2]) : "v"(lo), "v"(hi));
        }
        bf16x8 pf = pk.v;
#pragma unroll
        for (int dhg = 0; dhg < 4; ++dhg) {
          const char* vrow = (const char*)Vs[cur] + (dhg * 16 + lr) * 128;
          bf16x4 va = *(const bf16x4*)(vrow + ((half * 64 + lg * 8) ^ swz));
          bf16x4 vb = *(const bf16x4*)(vrow + ((half * 64 + 32 + lg * 8) ^ swz));
          bf16x8 vf = __builtin_shufflevector(va, vb, 0, 1, 2, 3, 4, 5, 6, 7);
          o[dhg] = __builtin_amdgcn_mfma_f32_16x16x32_bf16(pf, vf, o[dhg], 0, 0, 0);
        }
      }

      __syncthreads();
    }

    lrun += __shfl_xor(lrun, 16);
    lrun += __shfl_xor(lrun, 32);
    float linv = 1.0f / lrun;
#pragma unroll
    for (int r = 0; r < 4; ++r) {
      float lq = __shfl(linv, (l & 48) | (lg * 4 + r));
      int srow = qt * 128 + w * 16 + lg * 4 + r;
      size_t base = ((size_t)(b * NS + srow)) * (NH * NDH) + h * NDH;
#pragma unroll
      for (int dhg = 0; dhg < 4; ++dhg)
        CTX[base + dhg * 16 + lr] = f2bf(o[dhg][r] * lq);
    }
  }
#undef STAGE
}

// ---------------- launch ----------------
extern "C" void kernel_launch(void* const* d_in, const int* in_sizes, int n_in,
                              void* d_out, int out_size, void* d_ws, size_t ws_size,
                              hipStream_t stream) {
  const float* payload = (const float*)d_in[0];
  const float* w_qkv   = (const float*)d_in[1];
  const float* w_out   = (const float*)d_in[2];
  const float* b_out   = (const float*)d_in[3];
  float* out = (float*)d_out;

  char* ws = (char*)d_ws;
  size_t o0 = 0;
  u16* Xb    = (u16*)(ws + o0); o0 += (size_t)8192 * 1024 * 2;
  u16* Wqkvt = (u16*)(ws + o0); o0 += (size_t)3072 * 1024 * 2;
  u16* Woutt = (u16*)(ws + o0); o0 += (size_t)1024 * 1024 * 2;
  u16* Qb    = (u16*)(ws + o0); o0 += (size_t)64 * 2048 * 64 * 2;
  u16* Kb    = (u16*)(ws + o0); o0 += (size_t)64 * 2048 * 64 * 2;
  u16* VTb   = (u16*)(ws + o0); o0 += (size_t)64 * 64 * 2048 * 2;  // [bh][dh][s]
  u16* CTX   = Xb;  // alias: GEMM0 finishes reading Xb before attn writes CTX

  cvt_k<<<dim3(4096), dim3(256), 0, stream>>>(payload, Xb, 8192 * 1024);
  trcvt_k<<<dim3(96, 32), dim3(256), 0, stream>>>(w_qkv, Wqkvt, 1024, 3072);
  trcvt_k<<<dim3(32, 32), dim3(256), 0, stream>>>(w_out, Woutt, 1024, 1024);
  gemm8_k<<<dim3(24, 32), dim3(512), 0, stream>>>(Xb, Wqkvt, Qb, Kb, VTb);
  attn_k<<<dim3(64, 8), dim3(512), 0, stream>>>(Qb, Kb, VTb, CTX);
  gemm_k<2><<<dim3(8, 64), dim3(256), 0, stream>>>(CTX, Woutt, 8192, 1024, 1024,
                                                   out, b_out);
}

// Round 13
// 208.310 us; speedup vs baseline: 1.0566x; 1.0566x over previous
//
#include <hip/hip_runtime.h>

// Problem: B=4, S=2048, D_IN=1024, D_OUT=1024, H=16, DH=64
#define NB 4
#define NS 2048
#define NH 16
#define NDH 64

typedef short bf16x8 __attribute__((ext_vector_type(8)));
typedef short bf16x4 __attribute__((ext_vector_type(4)));
typedef float f32x4 __attribute__((ext_vector_type(4)));
typedef unsigned short u16;
typedef unsigned int u32;

static __device__ __forceinline__ u16 f2bf(float f) {
  unsigned u = __float_as_uint(f);
  u += 0x7fffu + ((u >> 16) & 1u);  // round-to-nearest-even
  return (u16)(u >> 16);
}

#define GLDS(gp, lp) __builtin_amdgcn_global_load_lds( \
    (const __attribute__((address_space(1))) void*)(gp), \
    (__attribute__((address_space(3))) void*)(lp), 16, 0, 0)

#define BAR   do { __builtin_amdgcn_s_barrier(); __builtin_amdgcn_sched_barrier(0); } while (0)
#define VMC(n) do { asm volatile("s_waitcnt vmcnt(" #n ")" ::: "memory"); \
                    __builtin_amdgcn_sched_barrier(0); } while (0)

// ---------------- fp32 -> bf16 elementwise convert ----------------
__global__ void cvt_k(const float* __restrict__ in, u16* __restrict__ out, int n) {
  int i = (blockIdx.x * 256 + threadIdx.x) * 8;
  if (i >= n) return;
  float4 a = *(const float4*)&in[i];
  float4 b = *(const float4*)&in[i + 4];
  bf16x8 u;
  u[0] = (short)f2bf(a.x); u[1] = (short)f2bf(a.y);
  u[2] = (short)f2bf(a.z); u[3] = (short)f2bf(a.w);
  u[4] = (short)f2bf(b.x); u[5] = (short)f2bf(b.y);
  u[6] = (short)f2bf(b.z); u[7] = (short)f2bf(b.w);
  *(bf16x8*)&out[i] = u;
}

// ---------------- fp32 [R][C] -> bf16 [C][R] transpose-convert ----------------
__global__ void trcvt_k(const float* __restrict__ in, u16* __restrict__ out, int R, int C) {
  __shared__ float t[32][33];
  int c0 = blockIdx.x * 32, r0 = blockIdx.y * 32;
  int tx = threadIdx.x & 7, ty = threadIdx.x >> 3;
  float4 v = *(const float4*)&in[(size_t)(r0 + ty) * C + c0 + tx * 4];
  t[ty][tx * 4 + 0] = v.x; t[ty][tx * 4 + 1] = v.y;
  t[ty][tx * 4 + 2] = v.z; t[ty][tx * 4 + 3] = v.w;
  __syncthreads();
  ushort4 o;
  o.x = f2bf(t[tx * 4 + 0][ty]); o.y = f2bf(t[tx * 4 + 1][ty]);
  o.z = f2bf(t[tx * 4 + 2][ty]); o.w = f2bf(t[tx * 4 + 3][ty]);
  *(ushort4*)&out[(size_t)(c0 + ty) * R + r0 + tx * 4] = o;
}

// ------- bf16 GEMM, BK=32, 3-buffer counted-vmcnt pipeline (T3/T4-lite) -------
// A [M][K], Bt [N][K] row-major. Tile BM=(WM*64) x 128; WM*2 waves, wave 64x64.
// Per K-tile (one phase): {8 ds_read_b128 frags + issue tile t+2's GLDS} ->
// barrier -> setprio 16 MFMA -> vmcnt(LPT: t+1 landed, t+2 in flight) -> barrier.
// Loads never drain to 0 in steady state; 72KB LDS (WM=4) -> 2 blocks/CU.
// 64B LDS rows: swizzle byte ^= (row&3)<<4 (bijective 4x4 16B-slot cover),
// source pre-swizzled (rule #21).
// MODE 0: scatter Q (pre-scaled 0.125*log2e) / K / VT.  MODE 1: fp32 + bias.
template<int MODE, int WM>
__global__ __launch_bounds__(WM * 128)
void gemm_k(const u16* __restrict__ A, const u16* __restrict__ Bt,
            int K, int N,
            u16* __restrict__ Qo, u16* __restrict__ Ko, u16* __restrict__ VTo,
            float* __restrict__ Co, const float* __restrict__ bias) {
  constexpr int T  = WM * 128;       // threads
  constexpr int BM = WM * 64;        // M-tile
  constexpr int RB = 512 / T;        // B staging rounds (rows 128, T/4 rows/round)
  constexpr int LPT = 2 + RB;        // GLDS per thread per tile
  __shared__ __align__(16) u16 As[3][BM * 32];
  __shared__ __align__(16) u16 Bs[3][128 * 32];
  const int tid = threadIdx.x;
  const int w = tid >> 6, l = tid & 63;
  const int lr = l & 15, lg = l >> 4;
  const int wr = w >> 1, wc = w & 1;
  const int m0 = blockIdx.y * BM, n0 = blockIdx.x * 128;

  f32x4 acc[4][4] = {};

  // staging maps: thread covers 16B at LDS byte (round*T + tid)*16; source row
  // = (round*T/4 + tid>>2), source col pre-swizzled.
  const int sb = ((tid & 3) * 16) ^ (((tid >> 2) & 3) << 4);
  const int srcA0 = (tid >> 2) * K + (sb >> 1);
  const int srcA1 = (T / 4 + (tid >> 2)) * K + (sb >> 1);
  int srcB[RB], dstB[RB];
#pragma unroll
  for (int r = 0; r < RB; ++r) {
    srcB[r] = (r * (T / 4) + (tid >> 2)) * K + (sb >> 1);
    dstB[r] = r * T * 16 + w * 1024;
  }
  const int dstA0 = w * 1024, dstA1 = T * 16 + w * 1024;

#define STG(t, buf) do {                                              \
    const u16* Ab_ = A  + (size_t)m0 * K + (t) * 32;                  \
    const u16* Bb_ = Bt + (size_t)n0 * K + (t) * 32;                  \
    GLDS(Ab_ + srcA0, (char*)As[buf] + dstA0);                        \
    GLDS(Ab_ + srcA1, (char*)As[buf] + dstA1);                        \
    _Pragma("unroll")                                                 \
    for (int r = 0; r < RB; ++r)                                      \
      GLDS(Bb_ + srcB[r], (char*)Bs[buf] + dstB[r]);                  \
  } while (0)

  const int rswz = (lr & 3) << 4;    // read-side XOR (row&3 == lr&3)
  const int nk = K >> 5;

  STG(0, 0);
  STG(1, 1);
  if constexpr (WM == 4) { VMC(3); } else { VMC(4); }   // tile 0 landed
  BAR;

  for (int t = 0; t < nk; ++t) {
    const int cur = t % 3;
    const char* Ar = (const char*)As[cur];
    const char* Br = (const char*)Bs[cur];
    bf16x8 af[4], bfr[4];
#pragma unroll
    for (int mi = 0; mi < 4; ++mi)
      af[mi] = *(const bf16x8*)(Ar + (wr * 64 + mi * 16 + lr) * 64 + ((lg * 16) ^ rswz));
#pragma unroll
    for (int ni = 0; ni < 4; ++ni)
      bfr[ni] = *(const bf16x8*)(Br + (wc * 64 + ni * 16 + lr) * 64 + ((lg * 16) ^ rswz));
    if (t + 2 < nk) STG(t + 2, (t + 2) % 3);   // overwrites buf (t-1)%3: consumed
    BAR;
    __builtin_amdgcn_s_setprio(1);
#pragma unroll
    for (int ni = 0; ni < 4; ++ni)
#pragma unroll
      for (int mi = 0; mi < 4; ++mi)
        acc[mi][ni] = __builtin_amdgcn_mfma_f32_16x16x32_bf16(af[mi], bfr[ni], acc[mi][ni], 0, 0, 0);
    __builtin_amdgcn_s_setprio(0);
    if (t + 2 < nk) {
      if constexpr (WM == 4) { VMC(3); } else { VMC(4); }  // t+1 landed; t+2 flying
    } else {
      VMC(0);                                              // tail drain
    }
    BAR;
  }

#pragma unroll
  for (int mi = 0; mi < 4; ++mi) {
#pragma unroll
    for (int ni = 0; ni < 4; ++ni) {
#pragma unroll
      for (int r = 0; r < 4; ++r) {
        int gm = m0 + wr * 64 + mi * 16 + lg * 4 + r;
        int gn = n0 + wc * 64 + ni * 16 + lr;
        float v = acc[mi][ni][r];
        if (MODE == 0) {
          int which = gn >> 10, hd = gn & 1023;
          int b = gm >> 11, s = gm & 2047;
          int bh = b * NH + (hd >> 6), dh = hd & 63;
          if (which == 0)      Qo[((size_t)bh * NS + s) * NDH + dh] = f2bf(v * 0.1803368801111204f);
          else if (which == 1) Ko[((size_t)bh * NS + s) * NDH + dh] = f2bf(v);
          else                 VTo[((size_t)bh * NDH + dh) * NS + s] = f2bf(v);
        } else {
          Co[(size_t)gm * N + gn] = v + bias[gn];
        }
      }
    }
  }
#undef STG
}

// ---------------- causal flash attention (unchanged from R9/R11) ----------------
__global__ __launch_bounds__(512)
void attn_k(const u16* __restrict__ Q, const u16* __restrict__ Kg,
            const u16* __restrict__ VTg, u16* __restrict__ CTX) {
  const int bh = blockIdx.x;
  const int pr = blockIdx.y;
  const int tid = threadIdx.x, w = tid >> 6, l = tid & 63;
  const int lr = l & 15, lg = l >> 4;
  const u16* Qh  = Q   + (size_t)bh * NS * NDH;
  const u16* Kh  = Kg  + (size_t)bh * NS * NDH;
  const u16* Vth = VTg + (size_t)bh * NDH * NS;

  __shared__ __align__(16) u16 Ks[2][64 * 64];
  __shared__ __align__(16) u16 Vs[2][64 * 64];

  const int srow_ = tid >> 3;
  const int colb  = (tid & 7) * 16;
  const int scolb = colb ^ ((srow_ & 7) << 4);
  const int kSrcOff = srow_ * NDH + (scolb >> 1);
  const int vSrcOff = srow_ * NS + (scolb >> 1);
  const int ldsOff  = w * 1024;

#define STAGE(t, buf) do {                                          \
    GLDS(Kh  + (size_t)(t) * 64 * NDH + kSrcOff, (char*)Ks[buf] + ldsOff); \
    GLDS(Vth + (size_t)(t) * 64       + vSrcOff, (char*)Vs[buf] + ldsOff); \
  } while (0)

  const int swz = (lr & 7) << 4;
  const int b = bh >> 4, h = bh & 15;

  for (int pass = 0; pass < 2; ++pass) {
    const int qt = pass == 0 ? pr : 15 - pr;

    const int qrow = qt * 128 + w * 16 + lr;
    bf16x8 qf[2];
    qf[0] = *(const bf16x8*)&Qh[(size_t)qrow * NDH + 0 * 32 + lg * 8];
    qf[1] = *(const bf16x8*)&Qh[(size_t)qrow * NDH + 1 * 32 + lg * 8];

    f32x4 o[4] = {};
    float lrun = 0.f;
    const int qmin = qt * 128 + w * 16;

    __syncthreads();
    STAGE(0, 0);
    __syncthreads();

    const int NT = 2 * qt + 2;
    for (int kt = 0; kt < NT; ++kt) {
      const int cur = kt & 1;
      if (kt + 1 < NT) STAGE(kt + 1, cur ^ 1);

      f32x4 sc[4] = {};
#pragma unroll
      for (int kk = 0; kk < 2; ++kk) {
#pragma unroll
        for (int kg = 0; kg < 4; ++kg) {
          bf16x8 kf = *(const bf16x8*)((const char*)Ks[cur] +
                       ((kg * 16 + lr) * 128 + ((kk * 64 + lg * 16) ^ swz)));
          sc[kg] = __builtin_amdgcn_mfma_f32_16x16x32_bf16(kf, qf[kk], sc[kg], 0, 0, 0);
        }
      }

      float sum = 0.f;
      if (kt * 64 + 63 > qmin) {
#pragma unroll
        for (int kg = 0; kg < 4; ++kg)
#pragma unroll
          for (int r = 0; r < 4; ++r) {
            int kglob = kt * 64 + kg * 16 + lg * 4 + r;
            float e = (kglob > qrow) ? 0.f : exp2f(sc[kg][r]);
            sc[kg][r] = e; sum += e;
          }
      } else {
#pragma unroll
        for (int kg = 0; kg < 4; ++kg)
#pragma unroll
          for (int r = 0; r < 4; ++r) {
            float e = exp2f(sc[kg][r]);
            sc[kg][r] = e; sum += e;
          }
      }
      lrun += sum;

#pragma unroll
      for (int half = 0; half < 2; ++half) {
        union { u32 wd[4]; bf16x8 v; } pk;
#pragma unroll
        for (int w2 = 0; w2 < 4; ++w2) {
          float lo = sc[half * 2 + (w2 >> 1)][2 * (w2 & 1)];
          float hi = sc[half * 2 + (w2 >> 1)][2 * (w2 & 1) + 1];
          asm("v_cvt_pk_bf16_f32 %0, %1, %2" : "=v"(pk.wd[w2]) : "v"(lo), "v"(hi));
        }
        bf16x8 pf = pk.v;
#pragma unroll
        for (int dhg = 0; dhg < 4; ++dhg) {
          const char* vrow = (const char*)Vs[cur] + (dhg * 16 + lr) * 128;
          bf16x4 va = *(const bf16x4*)(vrow + ((half * 64 + lg * 8) ^ swz));
          bf16x4 vb = *(const bf16x4*)(vrow + ((half * 64 + 32 + lg * 8) ^ swz));
          bf16x8 vf = __builtin_shufflevector(va, vb, 0, 1, 2, 3, 4, 5, 6, 7);
          o[dhg] = __builtin_amdgcn_mfma_f32_16x16x32_bf16(pf, vf, o[dhg], 0, 0, 0);
        }
      }

      __syncthreads();
    }

    lrun += __shfl_xor(lrun, 16);
    lrun += __shfl_xor(lrun, 32);
    float linv = 1.0f / lrun;
#pragma unroll
    for (int r = 0; r < 4; ++r) {
      float lq = __shfl(linv, (l & 48) | (lg * 4 + r));
      int srow = qt * 128 + w * 16 + lg * 4 + r;
      size_t base = ((size_t)(b * NS + srow)) * (NH * NDH) + h * NDH;
#pragma unroll
      for (int dhg = 0; dhg < 4; ++dhg)
        CTX[base + dhg * 16 + lr] = f2bf(o[dhg][r] * lq);
    }
  }
#undef STAGE
}

// ---------------- launch ----------------
extern "C" void kernel_launch(void* const* d_in, const int* in_sizes, int n_in,
                              void* d_out, int out_size, void* d_ws, size_t ws_size,
                              hipStream_t stream) {
  const float* payload = (const float*)d_in[0];
  const float* w_qkv   = (const float*)d_in[1];
  const float* w_out   = (const float*)d_in[2];
  const float* b_out   = (const float*)d_in[3];
  float* out = (float*)d_out;

  char* ws = (char*)d_ws;
  size_t o0 = 0;
  u16* Xb    = (u16*)(ws + o0); o0 += (size_t)8192 * 1024 * 2;
  u16* Wqkvt = (u16*)(ws + o0); o0 += (size_t)3072 * 1024 * 2;
  u16* Woutt = (u16*)(ws + o0); o0 += (size_t)1024 * 1024 * 2;
  u16* Qb    = (u16*)(ws + o0); o0 += (size_t)64 * 2048 * 64 * 2;
  u16* Kb    = (u16*)(ws + o0); o0 += (size_t)64 * 2048 * 64 * 2;
  u16* VTb   = (u16*)(ws + o0); o0 += (size_t)64 * 64 * 2048 * 2;  // [bh][dh][s]
  u16* CTX   = Xb;  // alias: GEMM0 finishes reading Xb before attn writes CTX

  cvt_k<<<dim3(4096), dim3(256), 0, stream>>>(payload, Xb, 8192 * 1024);
  trcvt_k<<<dim3(96, 32), dim3(256), 0, stream>>>(w_qkv, Wqkvt, 1024, 3072);
  trcvt_k<<<dim3(32, 32), dim3(256), 0, stream>>>(w_out, Woutt, 1024, 1024);
  gemm_k<0, 4><<<dim3(24, 32), dim3(512), 0, stream>>>(Xb, Wqkvt, 1024, 3072,
                                                       Qb, Kb, VTb, nullptr, nullptr);
  attn_k<<<dim3(64, 8), dim3(512), 0, stream>>>(Qb, Kb, VTb, CTX);
  gemm_k<1, 2><<<dim3(8, 64), dim3(256), 0, stream>>>(CTX, Woutt, 1024, 1024,
                                                      nullptr, nullptr, nullptr, out, b_out);
}

// Round 14
// 193.562 us; speedup vs baseline: 1.1371x; 1.0762x over previous
//
#include <hip/hip_runtime.h>

// Problem: B=4, S=2048, D_IN=1024, D_OUT=1024, H=16, DH=64
#define NB 4
#define NS 2048
#define NH 16
#define NDH 64

typedef short bf16x8 __attribute__((ext_vector_type(8)));
typedef short bf16x4 __attribute__((ext_vector_type(4)));
typedef float f32x4 __attribute__((ext_vector_type(4)));
typedef unsigned short u16;
typedef unsigned int u32;

static __device__ __forceinline__ u16 f2bf(float f) {
  unsigned u = __float_as_uint(f);
  u += 0x7fffu + ((u >> 16) & 1u);  // round-to-nearest-even
  return (u16)(u >> 16);
}

#define GLDS(gp, lp) __builtin_amdgcn_global_load_lds( \
    (const __attribute__((address_space(1))) void*)(gp), \
    (__attribute__((address_space(3))) void*)(lp), 16, 0, 0)

// ---------------- fp32 -> bf16 elementwise convert ----------------
__global__ void cvt_k(const float* __restrict__ in, u16* __restrict__ out, int n) {
  int i = (blockIdx.x * 256 + threadIdx.x) * 8;
  if (i >= n) return;
  float4 a = *(const float4*)&in[i];
  float4 b = *(const float4*)&in[i + 4];
  bf16x8 u;
  u[0] = (short)f2bf(a.x); u[1] = (short)f2bf(a.y);
  u[2] = (short)f2bf(a.z); u[3] = (short)f2bf(a.w);
  u[4] = (short)f2bf(b.x); u[5] = (short)f2bf(b.y);
  u[6] = (short)f2bf(b.z); u[7] = (short)f2bf(b.w);
  *(bf16x8*)&out[i] = u;
}

// ---------------- fp32 [R][C] -> bf16 [C][R] transpose-convert ----------------
__global__ void trcvt_k(const float* __restrict__ in, u16* __restrict__ out, int R, int C) {
  __shared__ float t[32][33];
  int c0 = blockIdx.x * 32, r0 = blockIdx.y * 32;
  int tx = threadIdx.x & 7, ty = threadIdx.x >> 3;
  float4 v = *(const float4*)&in[(size_t)(r0 + ty) * C + c0 + tx * 4];
  t[ty][tx * 4 + 0] = v.x; t[ty][tx * 4 + 1] = v.y;
  t[ty][tx * 4 + 2] = v.z; t[ty][tx * 4 + 3] = v.w;
  __syncthreads();
  ushort4 o;
  o.x = f2bf(t[tx * 4 + 0][ty]); o.y = f2bf(t[tx * 4 + 1][ty]);
  o.z = f2bf(t[tx * 4 + 2][ty]); o.w = f2bf(t[tx * 4 + 3][ty]);
  *(ushort4*)&out[(size_t)(c0 + ty) * R + r0 + tx * 4] = o;
}

// ---------------- bf16 GEMM, BK=64, XOR-swizzled LDS, 2-barrier loop ----------------
// R11 structure (best measured: 93us, 0 bank conflicts) + XCD-aware group-by-y
// block swizzle (T1): each XCD owns gridDim.y/8 contiguous y-panels, so the
// A-panel set is L2-resident per XCD and each B-tile is read by co-resident
// same-x blocks (1 miss + YG-1 hits) -> the per-K-tile vmcnt(0) drain waits on
// L2-hit latency (~200cy) instead of HBM (~900cy).
// MODE 0: scatter Q (pre-scaled 0.125*log2e) / K / VT.  MODE 1: fp32 + bias.
template<int MODE, int WM>
__global__ __launch_bounds__(WM * 128)
void gemm_k(const u16* __restrict__ A, const u16* __restrict__ Bt,
            int M, int N, int K,
            u16* __restrict__ Qo, u16* __restrict__ Ko, u16* __restrict__ VTo,
            float* __restrict__ Co, const float* __restrict__ bias) {
  constexpr int T  = WM * 128;       // threads
  constexpr int BM = WM * 64;        // M-tile
  constexpr int RA = 4;              // A staging rounds
  constexpr int RB = 1024 / T;       // B staging rounds
  __shared__ __align__(16) u16 As[BM * 64];
  __shared__ __align__(16) u16 Bs[128 * 64];
  const int tid = threadIdx.x;
  const int w = tid >> 6, l = tid & 63;
  const int lr = l & 15, lg = l >> 4;
  const int wr = w >> 1, wc = w & 1;

  // XCD-aware group-by-y swizzle (bijective: gridDim.y % 8 == 0 here)
  const int L = blockIdx.x + gridDim.x * blockIdx.y;
  const int xcd = L & 7, li = L >> 3;
  const int bx = li % gridDim.x;
  const int by = xcd * (gridDim.y >> 3) + li / gridDim.x;

  const int m0 = by * BM, n0 = bx * 128;
  const int swz = (lr & 7) << 4;

  f32x4 acc[4][4] = {};

  const int nk = K >> 6;
  for (int kt = 0; kt < nk; ++kt) {
    __syncthreads();                 // all waves done reading previous LDS tile
    const int k0 = kt * 64;
#pragma unroll
    for (int r2 = 0; r2 < RA; ++r2) {
      int c = r2 * T + tid;
      int row = c >> 3;
      int scolb = ((c & 7) * 16) ^ ((row & 7) << 4);   // inverse-swizzled source
      GLDS(A + (size_t)(m0 + row) * K + k0 + (scolb >> 1),
           (char*)As + (size_t)r2 * T * 16 + w * 1024);
    }
#pragma unroll
    for (int r2 = 0; r2 < RB; ++r2) {
      int c = r2 * T + tid;
      int row = c >> 3;
      int scolb = ((c & 7) * 16) ^ ((row & 7) << 4);
      GLDS(Bt + (size_t)(n0 + row) * K + k0 + (scolb >> 1),
           (char*)Bs + (size_t)r2 * T * 16 + w * 1024);
    }
    __syncthreads();                 // drains vmcnt(0): tile staged

#pragma unroll
    for (int kk = 0; kk < 2; ++kk) {
      bf16x8 af[4];
#pragma unroll
      for (int mi = 0; mi < 4; ++mi)
        af[mi] = *(const bf16x8*)((const char*)As +
                  ((wr * 64 + mi * 16 + lr) * 128 + ((kk * 64 + lg * 16) ^ swz)));
#pragma unroll
      for (int ni = 0; ni < 4; ++ni) {
        bf16x8 bfr = *(const bf16x8*)((const char*)Bs +
                  ((wc * 64 + ni * 16 + lr) * 128 + ((kk * 64 + lg * 16) ^ swz)));
#pragma unroll
        for (int mi = 0; mi < 4; ++mi)
          acc[mi][ni] = __builtin_amdgcn_mfma_f32_16x16x32_bf16(af[mi], bfr, acc[mi][ni], 0, 0, 0);
      }
    }
  }

#pragma unroll
  for (int mi = 0; mi < 4; ++mi) {
#pragma unroll
    for (int ni = 0; ni < 4; ++ni) {
#pragma unroll
      for (int r = 0; r < 4; ++r) {
        int gm = m0 + wr * 64 + mi * 16 + lg * 4 + r;
        int gn = n0 + wc * 64 + ni * 16 + lr;
        float v = acc[mi][ni][r];
        if (MODE == 0) {
          int which = gn >> 10, hd = gn & 1023;
          int b = gm >> 11, s = gm & 2047;
          int bh = b * NH + (hd >> 6), dh = hd & 63;
          if (which == 0)      Qo[((size_t)bh * NS + s) * NDH + dh] = f2bf(v * 0.1803368801111204f);
          else if (which == 1) Ko[((size_t)bh * NS + s) * NDH + dh] = f2bf(v);
          else                 VTo[((size_t)bh * NDH + dh) * NS + s] = f2bf(v);
        } else {
          Co[(size_t)gm * N + gn] = v + bias[gn];
        }
      }
    }
  }
}

// ---------------- causal flash attention (unchanged, R9-verified) ----------------
__global__ __launch_bounds__(512)
void attn_k(const u16* __restrict__ Q, const u16* __restrict__ Kg,
            const u16* __restrict__ VTg, u16* __restrict__ CTX) {
  const int bh = blockIdx.x;
  const int pr = blockIdx.y;
  const int tid = threadIdx.x, w = tid >> 6, l = tid & 63;
  const int lr = l & 15, lg = l >> 4;
  const u16* Qh  = Q   + (size_t)bh * NS * NDH;
  const u16* Kh  = Kg  + (size_t)bh * NS * NDH;
  const u16* Vth = VTg + (size_t)bh * NDH * NS;

  __shared__ __align__(16) u16 Ks[2][64 * 64];
  __shared__ __align__(16) u16 Vs[2][64 * 64];

  const int srow_ = tid >> 3;
  const int colb  = (tid & 7) * 16;
  const int scolb = colb ^ ((srow_ & 7) << 4);
  const int kSrcOff = srow_ * NDH + (scolb >> 1);
  const int vSrcOff = srow_ * NS + (scolb >> 1);
  const int ldsOff  = w * 1024;

#define STAGE(t, buf) do {                                          \
    GLDS(Kh  + (size_t)(t) * 64 * NDH + kSrcOff, (char*)Ks[buf] + ldsOff); \
    GLDS(Vth + (size_t)(t) * 64       + vSrcOff, (char*)Vs[buf] + ldsOff); \
  } while (0)

  const int swz = (lr & 7) << 4;
  const int b = bh >> 4, h = bh & 15;

  for (int pass = 0; pass < 2; ++pass) {
    const int qt = pass == 0 ? pr : 15 - pr;

    const int qrow = qt * 128 + w * 16 + lr;
    bf16x8 qf[2];
    qf[0] = *(const bf16x8*)&Qh[(size_t)qrow * NDH + 0 * 32 + lg * 8];
    qf[1] = *(const bf16x8*)&Qh[(size_t)qrow * NDH + 1 * 32 + lg * 8];

    f32x4 o[4] = {};
    float lrun = 0.f;
    const int qmin = qt * 128 + w * 16;

    __syncthreads();
    STAGE(0, 0);
    __syncthreads();

    const int NT = 2 * qt + 2;
    for (int kt = 0; kt < NT; ++kt) {
      const int cur = kt & 1;
      if (kt + 1 < NT) STAGE(kt + 1, cur ^ 1);

      f32x4 sc[4] = {};
#pragma unroll
      for (int kk = 0; kk < 2; ++kk) {
#pragma unroll
        for (int kg = 0; kg < 4; ++kg) {
          bf16x8 kf = *(const bf16x8*)((const char*)Ks[cur] +
                       ((kg * 16 + lr) * 128 + ((kk * 64 + lg * 16) ^ swz)));
          sc[kg] = __builtin_amdgcn_mfma_f32_16x16x32_bf16(kf, qf[kk], sc[kg], 0, 0, 0);
        }
      }

      float sum = 0.f;
      if (kt * 64 + 63 > qmin) {
#pragma unroll
        for (int kg = 0; kg < 4; ++kg)
#pragma unroll
          for (int r = 0; r < 4; ++r) {
            int kglob = kt * 64 + kg * 16 + lg * 4 + r;
            float e = (kglob > qrow) ? 0.f : exp2f(sc[kg][r]);
            sc[kg][r] = e; sum += e;
          }
      } else {
#pragma unroll
        for (int kg = 0; kg < 4; ++kg)
#pragma unroll
          for (int r = 0; r < 4; ++r) {
            float e = exp2f(sc[kg][r]);
            sc[kg][r] = e; sum += e;
          }
      }
      lrun += sum;

#pragma unroll
      for (int half = 0; half < 2; ++half) {
        union { u32 wd[4]; bf16x8 v; } pk;
#pragma unroll
        for (int w2 = 0; w2 < 4; ++w2) {
          float lo = sc[half * 2 + (w2 >> 1)][2 * (w2 & 1)];
          float hi = sc[half * 2 + (w2 >> 1)][2 * (w2 & 1) + 1];
          asm("v_cvt_pk_bf16_f32 %0, %1, %2" : "=v"(pk.wd[w2]) : "v"(lo), "v"(hi));
        }
        bf16x8 pf = pk.v;
#pragma unroll
        for (int dhg = 0; dhg < 4; ++dhg) {
          const char* vrow = (const char*)Vs[cur] + (dhg * 16 + lr) * 128;
          bf16x4 va = *(const bf16x4*)(vrow + ((half * 64 + lg * 8) ^ swz));
          bf16x4 vb = *(const bf16x4*)(vrow + ((half * 64 + 32 + lg * 8) ^ swz));
          bf16x8 vf = __builtin_shufflevector(va, vb, 0, 1, 2, 3, 4, 5, 6, 7);
          o[dhg] = __builtin_amdgcn_mfma_f32_16x16x32_bf16(pf, vf, o[dhg], 0, 0, 0);
        }
      }

      __syncthreads();
    }

    lrun += __shfl_xor(lrun, 16);
    lrun += __shfl_xor(lrun, 32);
    float linv = 1.0f / lrun;
#pragma unroll
    for (int r = 0; r < 4; ++r) {
      float lq = __shfl(linv, (l & 48) | (lg * 4 + r));
      int srow = qt * 128 + w * 16 + lg * 4 + r;
      size_t base = ((size_t)(b * NS + srow)) * (NH * NDH) + h * NDH;
#pragma unroll
      for (int dhg = 0; dhg < 4; ++dhg)
        CTX[base + dhg * 16 + lr] = f2bf(o[dhg][r] * lq);
    }
  }
#undef STAGE
}

// ---------------- launch ----------------
extern "C" void kernel_launch(void* const* d_in, const int* in_sizes, int n_in,
                              void* d_out, int out_size, void* d_ws, size_t ws_size,
                              hipStream_t stream) {
  const float* payload = (const float*)d_in[0];
  const float* w_qkv   = (const float*)d_in[1];
  const float* w_out   = (const float*)d_in[2];
  const float* b_out   = (const float*)d_in[3];
  float* out = (float*)d_out;

  char* ws = (char*)d_ws;
  size_t o0 = 0;
  u16* Xb    = (u16*)(ws + o0); o0 += (size_t)8192 * 1024 * 2;
  u16* Wqkvt = (u16*)(ws + o0); o0 += (size_t)3072 * 1024 * 2;
  u16* Woutt = (u16*)(ws + o0); o0 += (size_t)1024 * 1024 * 2;
  u16* Qb    = (u16*)(ws + o0); o0 += (size_t)64 * 2048 * 64 * 2;
  u16* Kb    = (u16*)(ws + o0); o0 += (size_t)64 * 2048 * 64 * 2;
  u16* VTb   = (u16*)(ws + o0); o0 += (size_t)64 * 64 * 2048 * 2;  // [bh][dh][s]
  u16* CTX   = Xb;  // alias: GEMM0 finishes reading Xb before attn writes CTX

  cvt_k<<<dim3(4096), dim3(256), 0, stream>>>(payload, Xb, 8192 * 1024);
  trcvt_k<<<dim3(96, 32), dim3(256), 0, stream>>>(w_qkv, Wqkvt, 1024, 3072);
  trcvt_k<<<dim3(32, 32), dim3(256), 0, stream>>>(w_out, Woutt, 1024, 1024);
  gemm_k<0, 4><<<dim3(24, 32), dim3(512), 0, stream>>>(Xb, Wqkvt, 8192, 3072, 1024,
                                                       Qb, Kb, VTb, nullptr, nullptr);
  attn_k<<<dim3(64, 8), dim3(512), 0, stream>>>(Qb, Kb, VTb, CTX);
  gemm_k<1, 2><<<dim3(8, 64), dim3(256), 0, stream>>>(CTX, Woutt, 8192, 1024, 1024,
                                                      nullptr, nullptr, nullptr, out, b_out);
}